// Round 12
// baseline (353.780 us; speedup 1.0000x reference)
//
#include <hip/hip_runtime.h>
#include <hip/hip_bf16.h>
#include <math.h>

#define NV 6890
#define BATCH 32
#define C720 720
#define HW 56
#define K2 1792          // x[0,720) 0[720,768) y[768,1488) 0[1488,1536) z[1536,1760) bias[1760,1763) 0..1792
#define NBIG 2048
#define MPAD 6912

typedef __attribute__((ext_vector_type(8))) short bf16x8;
typedef __attribute__((ext_vector_type(4))) float f32x4;

__device__ inline void gload16(const void* g, void* l) {
  __builtin_amdgcn_global_load_lds((const __attribute__((address_space(1))) void*)g,
                                   (__attribute__((address_space(3))) void*)l, 16, 0, 0);
}
__device__ inline float bf2f(short s) {
  union { unsigned u; float f; } c; c.u = ((unsigned)(unsigned short)s) << 16; return c.f;
}
__device__ inline short f2bf(float f) {
  __hip_bfloat16 h = (__hip_bfloat16)f; return *(short*)&h;
}

// ================= K1a: Mw1 (224 blocks, coalesced) | S + mb1 + deg-zero (1 block) =================
__global__ __launch_bounds__(256) void k_misc(
    const float* __restrict__ Wg1, const float* __restrict__ Ww1, const float* __restrict__ bw1,
    float* __restrict__ S, float* __restrict__ Mw1, float* __restrict__ mb1,
    int* __restrict__ deg) {
  const int blk = blockIdx.x, tid = threadIdx.x;
  if (blk < 224) {                                   // ---- Mw1[c][720] = mean_l Ww1 rows (row-major reads)
    const float* base = Ww1 + (size_t)blk * HW * 720;
    float a0 = 0.f, a1 = 0.f, a2 = 0.f;
    for (int l = 0; l < HW; ++l) {
      const float* r = base + (size_t)l * 720;
      a0 += r[tid];
      a1 += r[tid + 256];
      if (tid < 208) a2 += r[tid + 512];
    }
    float* d = Mw1 + (size_t)blk * 720;
    d[tid] = a0 * (1.f / HW);
    d[tid + 256] = a1 * (1.f / HW);
    if (tid < 208) d[tid + 512] = a2 * (1.f / HW);
    return;
  }
  if (tid < 64) {
    float s0 = 0, s1 = 0, s2 = 0;
    for (int l = 0; l < HW; ++l) {
      s0 += Wg1[l * 64 + tid];
      s1 += Wg1[(HW + l) * 64 + tid];
      s2 += Wg1[(112 + l) * 64 + tid];
    }
    S[tid] = s0; S[64 + tid] = s1; S[128 + tid] = s2;
  }
  if (tid < 224) {
    float s = 0.f;
    for (int l = 0; l < HW; ++l) s += bw1[tid * HW + l];
    mb1[tid] = s * (1.f / HW);
  }
  for (int v = tid; v < NV; v += 256) deg[v] = 0;
}

// ================= K1b: edge-degree histogram =================
__global__ __launch_bounds__(256) void k_deg(const int* __restrict__ ei, int E, int* __restrict__ deg) {
  int e = blockIdx.x * 256 + threadIdx.x;
  if (e < E) atomicAdd(&deg[ei[E + e]], 1);
}

// ================= K1c: scan (1 block) =================
__global__ __launch_bounds__(256) void k_scan(const int* __restrict__ deg,
    int* __restrict__ rowptr, float* __restrict__ dinv, int* __restrict__ cursor) {
  __shared__ int sdata[256];
  const int tid = threadIdx.x;
  const int PER = 27;
  int base = tid * PER, loc[PER], tot = 0;
  #pragma unroll
  for (int i = 0; i < PER; ++i) {
    int idx = base + i;
    int c = (idx < NV) ? deg[idx] + 1 : 0;           // +1 self-loop
    loc[i] = tot; tot += c;
    if (idx < NV) dinv[idx] = rsqrtf((float)c);
  }
  sdata[tid] = tot; __syncthreads();
  for (int off = 1; off < 256; off <<= 1) {
    int v2 = sdata[tid];
    int a = (tid >= off) ? sdata[tid - off] : 0;
    __syncthreads();
    sdata[tid] = v2 + a;
    __syncthreads();
  }
  int excl = sdata[tid] - tot;
  #pragma unroll
  for (int i = 0; i < PER; ++i) {
    int idx = base + i;
    if (idx < NV) { int r = excl + loc[i]; rowptr[idx] = r; cursor[idx] = r; }
  }
  if (tid == 255) rowptr[NV] = sdata[255];
}

// ================= K1d: CSR fill =================
__global__ __launch_bounds__(256) void k_fill(const int* __restrict__ ei, int E,
    int* __restrict__ cursor, int* __restrict__ colx) {
  int i = blockIdx.x * 256 + threadIdx.x;
  int N = E + NV;
  if (i >= N) return;
  int s, d;
  if (i < E) { s = ei[i]; d = ei[E + i]; } else { s = d = i - E; }
  colx[atomicAdd(&cursor[d], 1)] = s;
}

// ================= K2: wcat =================
__global__ __launch_bounds__(256) void k_wcat(const float* __restrict__ Wx, const float* __restrict__ Wy,
    const float* __restrict__ Wz2, const float* __restrict__ bx, const float* __restrict__ by,
    const float* __restrict__ bz2, __hip_bfloat16* __restrict__ Wcatb) {
  int idx = blockIdx.x * 256 + threadIdx.x;
  int v = idx / 224, c8 = (idx - v * 224) * 8;
  float val[8] = {};
  if (v < NV) {
    const float* s = nullptr;
    if (c8 < 720)                      s = Wx  + (size_t)v * 720 + c8;
    else if (c8 >= 768 && c8 < 1488)   s = Wy  + (size_t)v * 720 + (c8 - 768);
    else if (c8 >= 1536 && c8 < 1760)  s = Wz2 + (size_t)v * 224 + (c8 - 1536);
    if (s) {
      float4 a = *(const float4*)s, b4 = *(const float4*)(s + 4);
      val[0]=a.x; val[1]=a.y; val[2]=a.z; val[3]=a.w;
      val[4]=b4.x; val[5]=b4.y; val[6]=b4.z; val[7]=b4.w;
    } else if (c8 == 1760) {
      val[0] = bx[v]; val[1] = by[v]; val[2] = bz2[v];
    }
  }
  bf16x8 o;
  #pragma unroll
  for (int e = 0; e < 8; ++e) o[e] = f2bf(val[e]);
  *(bf16x8*)(Wcatb + (size_t)v * K2 + c8) = o;
}

// ================= K3: img reduction =================
__global__ __launch_bounds__(256) void k_imgred(const float* __restrict__ img,
    const float* __restrict__ Wg1, float* __restrict__ P, float* __restrict__ gT) {
  __shared__ float rsumS[64];
  __shared__ float cpartW[4][56];
  __shared__ float csumS[56];
  const int blk = blockIdx.x, tid = threadIdx.x;
  if (blk >= 5760) {                                  // zero P gap rows
    int r0 = (blk == 5760) ? 720 : 1488;
    float4* dst = (float4*)(P + (size_t)r0 * NBIG);
    for (int i = tid; i < 48 * NBIG / 4; i += 256) dst[i] = (float4){0.f, 0.f, 0.f, 0.f};
    return;
  }
  const int b = blk / C720, c = blk - b * C720;
  const float4* tp4 = (const float4*)(img + (size_t)blk * (HW * HW));
  const int wq = tid & 15, hg = tid >> 4;
  float4 cp = (float4){0.f, 0.f, 0.f, 0.f};
  #pragma unroll
  for (int r = 0; r < 4; ++r) {
    int h = hg + 16 * r;
    bool ok = (wq < 14) & (h < HW);
    float4 v = ok ? tp4[h * 14 + wq] : (float4){0.f, 0.f, 0.f, 0.f};
    cp.x += v.x; cp.y += v.y; cp.z += v.z; cp.w += v.w;
    float rsum = v.x + v.y + v.z + v.w;
    #pragma unroll
    for (int off = 1; off < 16; off <<= 1) rsum += __shfl_xor(rsum, off);
    if (wq == 0 && h < HW) rsumS[h] = rsum;
  }
  #pragma unroll
  for (int off = 16; off < 64; off <<= 1) {
    cp.x += __shfl_xor(cp.x, off); cp.y += __shfl_xor(cp.y, off);
    cp.z += __shfl_xor(cp.z, off); cp.w += __shfl_xor(cp.w, off);
  }
  int wave = tid >> 6, lane = tid & 63;
  if (lane < 14) *(float4*)&cpartW[wave][lane * 4] = cp;
  __syncthreads();
  if (tid < HW) csumS[tid] = cpartW[0][tid] + cpartW[1][tid] + cpartW[2][tid] + cpartW[3][tid];
  __syncthreads();
  if (tid < 64) {
    float ax = 0.f, ay = 0.f;
    #pragma unroll 4
    for (int l = 0; l < HW; ++l) {
      ax += csumS[l] * Wg1[l * 64 + tid];
      ay += rsumS[l] * Wg1[(HW + l) * 64 + tid];
    }
    P[(size_t)c * NBIG + b * 64 + tid] = ax * (1.f / HW);
    P[(size_t)(768 + c) * NBIG + b * 64 + tid] = ay * (1.f / HW);
  } else if (tid < 128) {
    int j = tid - 64;
    float s = (j < HW) ? csumS[j] : 0.f;
    #pragma unroll
    for (int off = 1; off < 64; off <<= 1) s += __shfl_xor(s, off);
    if (j == 0) gT[c * BATCH + b] = s * (1.f / (HW * HW));
  }
}

// ================= K4: Z1T, LDS-staged weight rows =================
__global__ __launch_bounds__(256) void k_head1(
    const float* __restrict__ Wz1, const float* __restrict__ bz1,
    const float* __restrict__ gT, float* __restrict__ Z1T) {
  __shared__ float Ws[8 * 720];
  const int blk = blockIdx.x, tid = threadIdx.x;
  const float* src = Wz1 + (size_t)blk * 8 * 720;
  for (int i = tid; i < 1440; i += 256)
    *(float4*)&Ws[i * 4] = *(const float4*)(src + i * 4);
  __syncthreads();
  int rg = tid >> 5, b = tid & 31;
  const float* wr = &Ws[rg * 720];
  float acc = 0.f;
  for (int k = 0; k < C720; k += 4) {
    float4 wv = *(const float4*)(wr + k);
    acc += wv.x * gT[(k    ) * 32 + b];
    acc += wv.y * gT[(k + 1) * 32 + b];
    acc += wv.z * gT[(k + 2) * 32 + b];
    acc += wv.w * gT[(k + 3) * 32 + b];
  }
  int r = blk * 8 + rg;
  Z1T[r * 32 + b] = acc + bz1[r];
}

// ================= K5: transp | z-head | bias cols | w1m =================
__global__ __launch_bounds__(256) void k_s3(const float* __restrict__ P,
    const float* __restrict__ Z1T, const float* __restrict__ Mw1, const float* __restrict__ mb1,
    const float* __restrict__ gT,
    const float* __restrict__ Wg1, const float* __restrict__ S,
    __hip_bfloat16* __restrict__ PT, float* __restrict__ w1m) {
  __shared__ float smem[5760];
  const int blk = blockIdx.x, tid = threadIdx.x;
  if (blk < 768) {
    __hip_bfloat16* t = (__hip_bfloat16*)smem;
    int k0 = (blk % 24) * 64, n0 = (blk / 24) * 64;
    int tx = tid & 63, ty4 = tid >> 6;
    #pragma unroll
    for (int i = 0; i < 16; ++i) {
      int k = ty4 * 16 + i;
      t[k * 66 + tx] = (__hip_bfloat16)P[(size_t)(k0 + k) * NBIG + n0 + tx];
    }
    __syncthreads();
    #pragma unroll
    for (int i = 0; i < 16; ++i) {
      int n = ty4 * 16 + i;
      PT[(size_t)(n0 + n) * K2 + k0 + tx] = t[tx * 66 + n];
    }
  } else if (blk < 992) {
    float* Zl = smem;
    float* Wz = smem + 1848;
    const int c = blk - 768;
    for (int i = tid; i < 1792; i += 256) {
      int l = i >> 5, b = i & 31;
      Zl[l * 33 + b] = Z1T[(size_t)c * 1792 + i];
    }
    for (int i = tid; i < 3584; i += 256) Wz[i] = Wg1[112 * 64 + i];
    __syncthreads();
    int n0 = tid * 8, b = n0 >> 6, j0 = n0 & 63;
    float a[8] = {};
    for (int l = 0; l < HW; ++l) {
      float zv = Zl[l * 33 + b];
      const float* wr = &Wz[l * 64 + j0];
      #pragma unroll
      for (int e = 0; e < 8; ++e) a[e] += zv * wr[e];
    }
    #pragma unroll
    for (int e = 0; e < 8; ++e)
      PT[(size_t)(n0 + e) * K2 + 1536 + c] = (__hip_bfloat16)a[e];
  } else if (blk < 1000) {
    int n = (blk - 992) * 256 + tid;
    int j = n & 63;
    bf16x8 o0 = {}, z = {};
    o0[0] = f2bf(S[j]); o0[1] = f2bf(S[64 + j]); o0[2] = f2bf(S[128 + j]);
    __hip_bfloat16* dst = PT + (size_t)n * K2 + 1760;
    *(bf16x8*)dst = o0;
    *(bf16x8*)(dst + 8) = z;
    *(bf16x8*)(dst + 16) = z;
    *(bf16x8*)(dst + 24) = z;
  } else {                                           // ---- w1m[c][b] = Mw1[c]·g[b] + mb1[c]
    int c0 = (blk - 1000) * 8;
    const float* src = Mw1 + (size_t)c0 * 720;
    for (int i = tid; i < 1440; i += 256)
      *(float4*)&smem[i * 4] = *(const float4*)(src + i * 4);
    __syncthreads();
    int rg = tid >> 5, b = tid & 31;
    const float* wr = &smem[rg * 720];
    float acc = 0.f;
    for (int k = 0; k < C720; k += 4) {
      float4 wv = *(const float4*)(wr + k);
      acc += wv.x * gT[(k    ) * 32 + b];
      acc += wv.y * gT[(k + 1) * 32 + b];
      acc += wv.z * gT[(k + 2) * 32 + b];
      acc += wv.w * gT[(k + 3) * 32 + b];
    }
    int c = c0 + rg;
    w1m[c * 32 + b] = acc + mb1[c];
  }
}

// ================= K6: wagg =================
__global__ __launch_bounds__(256) void k_wagg(const __hip_bfloat16* __restrict__ Wcatb,
    const int* __restrict__ rowptr, const int* __restrict__ colx, const float* __restrict__ dinv,
    __hip_bfloat16* __restrict__ Waggb) {
  int w = blockIdx.x * 4 + (threadIdx.x >> 6);
  int lane = threadIdx.x & 63;
  const int i3 = 1536 + lane * 8;
  const bool t3 = i3 < K2;
  __hip_bfloat16* drow = Waggb + (size_t)w * K2;
  if (w >= NV) {
    bf16x8 z = {};
    *(bf16x8*)(drow + lane * 8) = z;
    *(bf16x8*)(drow + 512 + lane * 8) = z;
    *(bf16x8*)(drow + 1024 + lane * 8) = z;
    if (t3) *(bf16x8*)(drow + i3) = z;
    return;
  }
  int r0 = rowptr[w], r1 = rowptr[w + 1];
  float a0[8] = {}, a1[8] = {}, a2[8] = {}, a3[8] = {};
  for (int i = r0; i < r1; ++i) {
    int u = colx[i];
    float wt = dinv[u];
    const __hip_bfloat16* row = Wcatb + (size_t)u * K2;
    bf16x8 x0 = *(const bf16x8*)(row + lane * 8);
    bf16x8 x1 = *(const bf16x8*)(row + 512 + lane * 8);
    bf16x8 x2 = *(const bf16x8*)(row + 1024 + lane * 8);
    #pragma unroll
    for (int e = 0; e < 8; ++e) {
      a0[e] += wt * bf2f(x0[e]);
      a1[e] += wt * bf2f(x1[e]);
      a2[e] += wt * bf2f(x2[e]);
    }
    if (t3) {
      bf16x8 x3 = *(const bf16x8*)(row + i3);
      #pragma unroll
      for (int e = 0; e < 8; ++e) a3[e] += wt * bf2f(x3[e]);
    }
  }
  float dv = dinv[w];
  bf16x8 o0, o1, o2, o3;
  #pragma unroll
  for (int e = 0; e < 8; ++e) {
    o0[e] = f2bf(a0[e] * dv); o1[e] = f2bf(a1[e] * dv);
    o2[e] = f2bf(a2[e] * dv); o3[e] = f2bf(a3[e] * dv);
  }
  *(bf16x8*)(drow + lane * 8) = o0;
  *(bf16x8*)(drow + 512 + lane * 8) = o1;
  *(bf16x8*)(drow + 1024 + lane * 8) = o2;
  if (t3) *(bf16x8*)(drow + i3) = o3;
}

// ================= K7: bf16 MFMA GEMM (m97 128², XCD-swizzled): p1 = dinv*leaky(Wagg @ PT^T + bg1) =================
__global__ __launch_bounds__(256) void k_mfma_gemm(
    const __hip_bfloat16* __restrict__ A, const __hip_bfloat16* __restrict__ BT,
    const float* __restrict__ bg1, const float* __restrict__ dinv,
    __hip_bfloat16* __restrict__ p1) {
  __shared__ __hip_bfloat16 As[128 * 64];
  __shared__ __hip_bfloat16 Bs[128 * 64];
  const int tid = threadIdx.x;
  const int wid = tid >> 6, lane = tid & 63;
  const int orig = blockIdx.y * gridDim.x + blockIdx.x;   // 864 blocks, 108/XCD
  const int swz = (orig & 7) * 108 + (orig >> 3);
  const int bxid = swz % (MPAD / 128), byid = swz / (MPAD / 128);
  const int m0 = bxid * 128, n0 = byid * 128;
  const int wr = wid >> 1, wc = wid & 1;
  const int l15 = lane & 15, lhi = lane >> 4;
  const int lk = lhi * 8;

  f32x4 acc[4][4];
  #pragma unroll
  for (int i = 0; i < 4; ++i)
    #pragma unroll
    for (int j = 0; j < 4; ++j) acc[i][j] = (f32x4){0.f, 0.f, 0.f, 0.f};

  const __hip_bfloat16* ag = A  + (size_t)(m0 + (tid >> 3)) * K2 + (tid & 7) * 8;
  const __hip_bfloat16* bg = BT + (size_t)(n0 + (tid >> 3)) * K2 + (tid & 7) * 8;
  const int lbase = wid * 512;

  for (int kt = 0; kt < K2; kt += 64) {
    #pragma unroll
    for (int p = 0; p < 4; ++p) {
      gload16(ag + kt + (size_t)(p * 32) * K2, (void*)&As[p * 2048 + lbase]);
      gload16(bg + kt + (size_t)(p * 32) * K2, (void*)&Bs[p * 2048 + lbase]);
    }
    __syncthreads();
    #pragma unroll
    for (int ks = 0; ks < 2; ++ks) {
      bf16x8 af[4], bf[4];
      #pragma unroll
      for (int mf = 0; mf < 4; ++mf)
        af[mf] = *(const bf16x8*)&As[(wr * 64 + mf * 16 + l15) * 64 + ks * 32 + lk];
      #pragma unroll
      for (int nf = 0; nf < 4; ++nf)
        bf[nf] = *(const bf16x8*)&Bs[(wc * 64 + nf * 16 + l15) * 64 + ks * 32 + lk];
      #pragma unroll
      for (int mf = 0; mf < 4; ++mf)
        #pragma unroll
        for (int nf = 0; nf < 4; ++nf)
          acc[mf][nf] = __builtin_amdgcn_mfma_f32_16x16x32_bf16(af[mf], bf[nf], acc[mf][nf], 0, 0, 0);
    }
    __syncthreads();
  }

  float bgv[4];
  #pragma unroll
  for (int nf = 0; nf < 4; ++nf) bgv[nf] = bg1[nf * 16 + l15];
  #pragma unroll
  for (int mf = 0; mf < 4; ++mf) {
    #pragma unroll
    for (int r = 0; r < 4; ++r) {
      int v = m0 + wr * 64 + mf * 16 + lhi * 4 + r;
      if (v >= NV) continue;
      float dv = dinv[v];
      __hip_bfloat16* pr = p1 + (size_t)v * NBIG + n0 + wc * 64;
      #pragma unroll
      for (int nf = 0; nf < 4; ++nf) {
        int jj = nf * 16 + l15;
        float x = acc[mf][nf][r] + bgv[nf];
        x = x > 0.f ? x : 0.01f * x;
        pr[jj] = (__hip_bfloat16)(x * dv);
      }
    }
  }
}

// ================= K8: coordw =================
__global__ __launch_bounds__(256) void k_coordw(const float* __restrict__ Ww2, const float* __restrict__ bw2,
    const float* __restrict__ w1m, float* __restrict__ out) {
  int v = blockIdx.x * 8 + (threadIdx.x >> 5);
  int b = threadIdx.x & 31;
  if (v >= NV) return;
  const float* wr = Ww2 + (size_t)v * 224;
  float acc = 0.f;
  for (int c = 0; c < 224; c += 4) {
    float4 wv = *(const float4*)(wr + c);
    acc += wv.x * w1m[(c    ) * 32 + b];
    acc += wv.y * w1m[(c + 1) * 32 + b];
    acc += wv.z * w1m[(c + 2) * 32 + b];
    acc += wv.w * w1m[(c + 3) * 32 + b];
  }
  acc += bw2[v];
  out[((size_t)b * NV + v) * 4 + 3] = 1.f / (1.f + expf(-acc));
}

// ================= K9: layer2 — block per vertex =================
__global__ __launch_bounds__(256) void k_t1(const __hip_bfloat16* __restrict__ p1,
    const int* __restrict__ rowptr, const int* __restrict__ colx, const float* __restrict__ dinv,
    const float* __restrict__ Wg2, const float* __restrict__ bg2, __hip_bfloat16* __restrict__ p2) {
  __shared__ float wg[2048];
  __shared__ float g[32 * 66];
  const int v = blockIdx.x, tid = threadIdx.x;
  for (int i = tid; i < 2048; i += 256) wg[i] = Wg2[i];
  const int r0 = rowptr[v], r1 = rowptr[v + 1];
  const int b = tid >> 3, j0 = (tid & 7) * 8;
  float a[8] = {};
  const short* base = (const short*)p1 + tid * 8;
  for (int i = r0; i < r1; ++i) {
    int u = colx[i];
    bf16x8 x = *(const bf16x8*)(base + (size_t)u * NBIG);
    #pragma unroll
    for (int e = 0; e < 8; ++e) a[e] += bf2f(x[e]);
  }
  #pragma unroll
  for (int e = 0; e < 8; e += 2)
    *(float2*)&g[b * 66 + j0 + e] = (float2){a[e], a[e + 1]};
  __syncthreads();
  const float dv = dinv[v];
  const int jg = tid & 7;
  float o0 = 0.f, o1 = 0.f, o2 = 0.f, o3 = 0.f;
  const float* gr = &g[b * 66];
  #pragma unroll 8
  for (int j = 0; j < 64; ++j) {
    float s = gr[j];
    const float* w = &wg[j * 32 + jg];
    o0 += s * w[0]; o1 += s * w[8]; o2 += s * w[16]; o3 += s * w[24];
  }
  __hip_bfloat16* pr = p2 + (size_t)v * 1024 + b * 32 + jg;
  float x0 = o0 * dv + bg2[jg];       x0 = x0 > 0.f ? x0 : 0.01f * x0;
  float x1 = o1 * dv + bg2[jg + 8];   x1 = x1 > 0.f ? x1 : 0.01f * x1;
  float x2 = o2 * dv + bg2[jg + 16];  x2 = x2 > 0.f ? x2 : 0.01f * x2;
  float x3 = o3 * dv + bg2[jg + 24];  x3 = x3 > 0.f ? x3 : 0.01f * x3;
  pr[0]  = (__hip_bfloat16)(x0 * dv);
  pr[8]  = (__hip_bfloat16)(x1 * dv);
  pr[16] = (__hip_bfloat16)(x2 * dv);
  pr[24] = (__hip_bfloat16)(x3 * dv);
}

// ================= K10: layer3 — block per vertex -> out[...,0:3) =================
__global__ __launch_bounds__(128) void k_t2(const __hip_bfloat16* __restrict__ p2,
    const int* __restrict__ rowptr, const int* __restrict__ colx, const float* __restrict__ dinv,
    const float* __restrict__ Wg3, const float* __restrict__ bg3, float* __restrict__ out) {
  __shared__ float wg[96];
  __shared__ float g[32 * 33];
  const int v = blockIdx.x, tid = threadIdx.x;
  if (tid < 96) wg[tid] = Wg3[tid];
  const int r0 = rowptr[v], r1 = rowptr[v + 1];
  const int b = tid >> 2, j0 = (tid & 3) * 8;
  float a[8] = {};
  const short* base = (const short*)p2 + tid * 8;
  for (int i = r0; i < r1; ++i) {
    int u = colx[i];
    bf16x8 x = *(const bf16x8*)(base + (size_t)u * 1024);
    #pragma unroll
    for (int e = 0; e < 8; ++e) a[e] += bf2f(x[e]);
  }
  #pragma unroll
  for (int e = 0; e < 8; ++e) g[b * 33 + j0 + e] = a[e];
  __syncthreads();
  if (tid < 96) {
    int bb = tid & 31, k = tid >> 5;
    float acc = 0.f;
    #pragma unroll 8
    for (int j2 = 0; j2 < 32; ++j2)
      acc += g[bb * 33 + j2] * wg[j2 * 3 + k];
    out[((size_t)bb * NV + v) * 4 + k] = acc * dinv[v] + bg3[k];
  }
}

extern "C" void kernel_launch(void* const* d_in, const int* in_sizes, int n_in,
                              void* d_out, int out_size, void* d_ws, size_t ws_size,
                              hipStream_t stream) {
  const float* img = (const float*)d_in[0];
  const int*   ei  = (const int*)d_in[1];
  const float* Wx  = (const float*)d_in[2];
  const float* bx  = (const float*)d_in[3];
  const float* Wy  = (const float*)d_in[4];
  const float* by  = (const float*)d_in[5];
  const float* Wz1 = (const float*)d_in[6];
  const float* bz1 = (const float*)d_in[7];
  const float* Wz2 = (const float*)d_in[8];
  const float* bz2 = (const float*)d_in[9];
  const float* Ww1 = (const float*)d_in[10];
  const float* bw1 = (const float*)d_in[11];
  const float* Ww2 = (const float*)d_in[12];
  const float* bw2 = (const float*)d_in[13];
  const float* Wg1 = (const float*)d_in[14];
  const float* bg1 = (const float*)d_in[15];
  const float* Wg2 = (const float*)d_in[16];
  const float* bg2 = (const float*)d_in[17];
  const float* Wg3 = (const float*)d_in[18];
  const float* bg3 = (const float*)d_in[19];
  float* out = (float*)d_out;
  int E = in_sizes[1] / 2;

  char* ws = (char*)d_ws;
  __hip_bfloat16* p1     = (__hip_bfloat16*)(ws + 0ULL);          // 28,311,552 [6912][2048]
  __hip_bfloat16* p2     = (__hip_bfloat16*)(ws + 28311552ULL);   // 14,155,776 [6912][1024]
  __hip_bfloat16* Wcatb  = (__hip_bfloat16*)(ws + 42467328ULL);   // 24,772,608 [6912][1792]
  __hip_bfloat16* Waggb  = (__hip_bfloat16*)(ws + 67239936ULL);   // 24,772,608
  float*          P      = (float*)(ws + 92012544ULL);            // 12,582,912 [1536][2048]
  __hip_bfloat16* PT     = (__hip_bfloat16*)(ws + 104595456ULL);  //  7,340,032 [2048][1792]
  float*          Z1T    = (float*)(ws + 111935488ULL);           //  1,605,632
  float*          Mw1    = (float*)(ws + 113541120ULL);           //    645,120 [224][720]
  float*          gT     = (float*)(ws + 114186240ULL);           //     92,160
  float*          w1m    = (float*)(ws + 114278400ULL);           //     28,672
  float*          S      = (float*)(ws + 114307072ULL);           //      1,024
  float*          mb1    = (float*)(ws + 114308096ULL);           //      1,024
  float*          dinv   = (float*)(ws + 114309120ULL);           //     27,648
  int*            rowptr = (int*)(ws + 114336768ULL);             //     27,648
  int*            colx   = (int*)(ws + 114364416ULL);             //    196,608
  int*            deg    = (int*)(ws + 114561024ULL);             //     27,648
  int*            cursor = (int*)(ws + 114588672ULL);             //     27,648

  k_misc<<<225, 256, 0, stream>>>(Wg1, Ww1, bw1, S, Mw1, mb1, deg);
  k_deg<<<(E + 255) / 256, 256, 0, stream>>>(ei, E, deg);
  k_scan<<<1, 256, 0, stream>>>(deg, rowptr, dinv, cursor);
  k_fill<<<(E + NV + 255) / 256, 256, 0, stream>>>(ei, E, cursor, colx);
  k_wcat<<<6048, 256, 0, stream>>>(Wx, Wy, Wz2, bx, by, bz2, Wcatb);
  k_imgred<<<5762, 256, 0, stream>>>(img, Wg1, P, gT);
  k_head1<<<1568, 256, 0, stream>>>(Wz1, bz1, gT, Z1T);
  k_s3<<<1028, 256, 0, stream>>>(P, Z1T, Mw1, mb1, gT, Wg1, S, PT, w1m);
  k_wagg<<<MPAD / 4, 256, 0, stream>>>(Wcatb, rowptr, colx, dinv, Waggb);
  k_mfma_gemm<<<dim3(MPAD / 128, NBIG / 128), 256, 0, stream>>>(Waggb, PT, bg1, dinv, p1);
  k_coordw<<<862, 256, 0, stream>>>(Ww2, bw2, w1m, out);
  k_t1<<<NV, 256, 0, stream>>>(p1, rowptr, colx, dinv, Wg2, bg2, p2);
  k_t2<<<NV, 128, 0, stream>>>(p2, rowptr, colx, dinv, Wg3, bg3, out);
}

// Round 13
// 326.417 us; speedup vs baseline: 1.0838x; 1.0838x over previous
//
#include <hip/hip_runtime.h>
#include <hip/hip_bf16.h>
#include <math.h>

#define NV 6890
#define BATCH 32
#define C720 720
#define HW 56
#define K2 1792          // x[0,720) 0[720,768) y[768,1488) 0[1488,1536) z[1536,1760) bias[1760,1763) 0..1792
#define NBIG 2048
#define MPAD 6912

typedef __attribute__((ext_vector_type(8))) short bf16x8;
typedef __attribute__((ext_vector_type(4))) float f32x4;

__device__ inline void gload16(const void* g, void* l) {
  __builtin_amdgcn_global_load_lds((const __attribute__((address_space(1))) void*)g,
                                   (__attribute__((address_space(3))) void*)l, 16, 0, 0);
}
__device__ inline float bf2f(short s) {
  union { unsigned u; float f; } c; c.u = ((unsigned)(unsigned short)s) << 16; return c.f;
}
__device__ inline short f2bf(float f) {
  __hip_bfloat16 h = (__hip_bfloat16)f; return *(short*)&h;
}

// ================= K1: FRONT mega-kernel =================
// blk [0,5762): imgred (+P gap zero) | [5762,11810): wcat | [11810,12482): Mw1 (672 strided)
// blk 12482: S + mb1 + deg-zero.  All sections depend only on inputs; share HBM pipe.
__global__ __launch_bounds__(256) void k_front(const float* __restrict__ img,
    const float* __restrict__ Wg1,
    const float* __restrict__ Wx, const float* __restrict__ Wy, const float* __restrict__ Wz2,
    const float* __restrict__ bx, const float* __restrict__ by, const float* __restrict__ bz2,
    const float* __restrict__ Ww1, const float* __restrict__ bw1,
    float* __restrict__ P, float* __restrict__ gT, __hip_bfloat16* __restrict__ Wcatb,
    float* __restrict__ S, float* __restrict__ Mw1, float* __restrict__ mb1,
    int* __restrict__ deg) {
  __shared__ float rsumS[64];
  __shared__ float cpartW[4][56];
  __shared__ float csumS[56];
  const int blk = blockIdx.x, tid = threadIdx.x;
  if (blk < 5760) {                                  // ---- img tile reduction
    const int b = blk / C720, c = blk - b * C720;
    const float4* tp4 = (const float4*)(img + (size_t)blk * (HW * HW));
    const int wq = tid & 15, hg = tid >> 4;
    float4 cp = (float4){0.f, 0.f, 0.f, 0.f};
    #pragma unroll
    for (int r = 0; r < 4; ++r) {
      int h = hg + 16 * r;
      bool ok = (wq < 14) & (h < HW);
      float4 v = ok ? tp4[h * 14 + wq] : (float4){0.f, 0.f, 0.f, 0.f};
      cp.x += v.x; cp.y += v.y; cp.z += v.z; cp.w += v.w;
      float rsum = v.x + v.y + v.z + v.w;
      #pragma unroll
      for (int off = 1; off < 16; off <<= 1) rsum += __shfl_xor(rsum, off);
      if (wq == 0 && h < HW) rsumS[h] = rsum;
    }
    #pragma unroll
    for (int off = 16; off < 64; off <<= 1) {
      cp.x += __shfl_xor(cp.x, off); cp.y += __shfl_xor(cp.y, off);
      cp.z += __shfl_xor(cp.z, off); cp.w += __shfl_xor(cp.w, off);
    }
    int wave = tid >> 6, lane = tid & 63;
    if (lane < 14) *(float4*)&cpartW[wave][lane * 4] = cp;
    __syncthreads();
    if (tid < HW) csumS[tid] = cpartW[0][tid] + cpartW[1][tid] + cpartW[2][tid] + cpartW[3][tid];
    __syncthreads();
    if (tid < 64) {
      float ax = 0.f, ay = 0.f;
      #pragma unroll 4
      for (int l = 0; l < HW; ++l) {
        ax += csumS[l] * Wg1[l * 64 + tid];
        ay += rsumS[l] * Wg1[(HW + l) * 64 + tid];
      }
      P[(size_t)c * NBIG + b * 64 + tid] = ax * (1.f / HW);
      P[(size_t)(768 + c) * NBIG + b * 64 + tid] = ay * (1.f / HW);
    } else if (tid < 128) {
      int j = tid - 64;
      float s = (j < HW) ? csumS[j] : 0.f;
      #pragma unroll
      for (int off = 1; off < 64; off <<= 1) s += __shfl_xor(s, off);
      if (j == 0) gT[c * BATCH + b] = s * (1.f / (HW * HW));
    }
  } else if (blk < 5762) {                           // ---- zero P gap rows
    int r0 = (blk == 5760) ? 720 : 1488;
    float4* dst = (float4*)(P + (size_t)r0 * NBIG);
    for (int i = tid; i < 48 * NBIG / 4; i += 256) dst[i] = (float4){0.f, 0.f, 0.f, 0.f};
  } else if (blk < 11810) {                          // ---- wcat
    int idx = (blk - 5762) * 256 + tid;
    int v = idx / 224, c8 = (idx - v * 224) * 8;
    float val[8] = {};
    if (v < NV) {
      const float* s = nullptr;
      if (c8 < 720)                      s = Wx  + (size_t)v * 720 + c8;
      else if (c8 >= 768 && c8 < 1488)   s = Wy  + (size_t)v * 720 + (c8 - 768);
      else if (c8 >= 1536 && c8 < 1760)  s = Wz2 + (size_t)v * 224 + (c8 - 1536);
      if (s) {
        float4 a = *(const float4*)s, b4 = *(const float4*)(s + 4);
        val[0]=a.x; val[1]=a.y; val[2]=a.z; val[3]=a.w;
        val[4]=b4.x; val[5]=b4.y; val[6]=b4.z; val[7]=b4.w;
      } else if (c8 == 1760) {
        val[0] = bx[v]; val[1] = by[v]; val[2] = bz2[v];
      }
    }
    bf16x8 o;
    #pragma unroll
    for (int e = 0; e < 8; ++e) o[e] = f2bf(val[e]);
    *(bf16x8*)(Wcatb + (size_t)v * K2 + c8) = o;
  } else if (blk < 12482) {                          // ---- Mw1[224][720], strided (r10-best variant)
    int q = blk - 11810;
    int c = q / 3, chunk = q - c * 3;
    if (tid < 240) {
      int k = chunk * 240 + tid;
      float s = 0.f;
      for (int l = 0; l < HW; ++l) s += Ww1[(size_t)(c * HW + l) * 720 + k];
      Mw1[c * 720 + k] = s * (1.f / HW);
    }
  } else {                                           // ---- S + mb1 + deg zero
    if (tid < 64) {
      float s0 = 0, s1 = 0, s2 = 0;
      for (int l = 0; l < HW; ++l) {
        s0 += Wg1[l * 64 + tid];
        s1 += Wg1[(HW + l) * 64 + tid];
        s2 += Wg1[(112 + l) * 64 + tid];
      }
      S[tid] = s0; S[64 + tid] = s1; S[128 + tid] = s2;
    }
    if (tid < 224) {
      float s = 0.f;
      for (int l = 0; l < HW; ++l) s += bw1[tid * HW + l];
      mb1[tid] = s * (1.f / HW);
    }
    for (int v = tid; v < NV; v += 256) deg[v] = 0;
  }
}

// ================= K1b: edge-degree histogram =================
__global__ __launch_bounds__(256) void k_deg(const int* __restrict__ ei, int E, int* __restrict__ deg) {
  int e = blockIdx.x * 256 + threadIdx.x;
  if (e < E) atomicAdd(&deg[ei[E + e]], 1);
}

// ================= K1c: scan (1 block) =================
__global__ __launch_bounds__(256) void k_scan(const int* __restrict__ deg,
    int* __restrict__ rowptr, float* __restrict__ dinv, int* __restrict__ cursor) {
  __shared__ int sdata[256];
  const int tid = threadIdx.x;
  const int PER = 27;
  int base = tid * PER, loc[PER], tot = 0;
  #pragma unroll
  for (int i = 0; i < PER; ++i) {
    int idx = base + i;
    int c = (idx < NV) ? deg[idx] + 1 : 0;           // +1 self-loop
    loc[i] = tot; tot += c;
    if (idx < NV) dinv[idx] = rsqrtf((float)c);
  }
  sdata[tid] = tot; __syncthreads();
  for (int off = 1; off < 256; off <<= 1) {
    int v2 = sdata[tid];
    int a = (tid >= off) ? sdata[tid - off] : 0;
    __syncthreads();
    sdata[tid] = v2 + a;
    __syncthreads();
  }
  int excl = sdata[tid] - tot;
  #pragma unroll
  for (int i = 0; i < PER; ++i) {
    int idx = base + i;
    if (idx < NV) { int r = excl + loc[i]; rowptr[idx] = r; cursor[idx] = r; }
  }
  if (tid == 255) rowptr[NV] = sdata[255];
}

// ================= K1d: CSR fill =================
__global__ __launch_bounds__(256) void k_fill(const int* __restrict__ ei, int E,
    int* __restrict__ cursor, int* __restrict__ colx) {
  int i = blockIdx.x * 256 + threadIdx.x;
  int N = E + NV;
  if (i >= N) return;
  int s, d;
  if (i < E) { s = ei[i]; d = ei[E + i]; } else { s = d = i - E; }
  colx[atomicAdd(&cursor[d], 1)] = s;
}

// ================= K4: Z1T, LDS-staged weight rows =================
__global__ __launch_bounds__(256) void k_head1(
    const float* __restrict__ Wz1, const float* __restrict__ bz1,
    const float* __restrict__ gT, float* __restrict__ Z1T) {
  __shared__ float Ws[8 * 720];
  const int blk = blockIdx.x, tid = threadIdx.x;
  const float* src = Wz1 + (size_t)blk * 8 * 720;
  for (int i = tid; i < 1440; i += 256)
    *(float4*)&Ws[i * 4] = *(const float4*)(src + i * 4);
  __syncthreads();
  int rg = tid >> 5, b = tid & 31;
  const float* wr = &Ws[rg * 720];
  float acc = 0.f;
  for (int k = 0; k < C720; k += 4) {
    float4 wv = *(const float4*)(wr + k);
    acc += wv.x * gT[(k    ) * 32 + b];
    acc += wv.y * gT[(k + 1) * 32 + b];
    acc += wv.z * gT[(k + 2) * 32 + b];
    acc += wv.w * gT[(k + 3) * 32 + b];
  }
  int r = blk * 8 + rg;
  Z1T[r * 32 + b] = acc + bz1[r];
}

// ================= K5: transp | z-head | bias cols | w1m =================
__global__ __launch_bounds__(256) void k_s3(const float* __restrict__ P,
    const float* __restrict__ Z1T, const float* __restrict__ Mw1, const float* __restrict__ mb1,
    const float* __restrict__ gT,
    const float* __restrict__ Wg1, const float* __restrict__ S,
    __hip_bfloat16* __restrict__ PT, float* __restrict__ w1m) {
  __shared__ float smem[5760];
  const int blk = blockIdx.x, tid = threadIdx.x;
  if (blk < 768) {
    __hip_bfloat16* t = (__hip_bfloat16*)smem;
    int k0 = (blk % 24) * 64, n0 = (blk / 24) * 64;
    int tx = tid & 63, ty4 = tid >> 6;
    #pragma unroll
    for (int i = 0; i < 16; ++i) {
      int k = ty4 * 16 + i;
      t[k * 66 + tx] = (__hip_bfloat16)P[(size_t)(k0 + k) * NBIG + n0 + tx];
    }
    __syncthreads();
    #pragma unroll
    for (int i = 0; i < 16; ++i) {
      int n = ty4 * 16 + i;
      PT[(size_t)(n0 + n) * K2 + k0 + tx] = t[tx * 66 + n];
    }
  } else if (blk < 992) {
    float* Zl = smem;
    float* Wz = smem + 1848;
    const int c = blk - 768;
    for (int i = tid; i < 1792; i += 256) {
      int l = i >> 5, b = i & 31;
      Zl[l * 33 + b] = Z1T[(size_t)c * 1792 + i];
    }
    for (int i = tid; i < 3584; i += 256) Wz[i] = Wg1[112 * 64 + i];
    __syncthreads();
    int n0 = tid * 8, b = n0 >> 6, j0 = n0 & 63;
    float a[8] = {};
    for (int l = 0; l < HW; ++l) {
      float zv = Zl[l * 33 + b];
      const float* wr = &Wz[l * 64 + j0];
      #pragma unroll
      for (int e = 0; e < 8; ++e) a[e] += zv * wr[e];
    }
    #pragma unroll
    for (int e = 0; e < 8; ++e)
      PT[(size_t)(n0 + e) * K2 + 1536 + c] = (__hip_bfloat16)a[e];
  } else if (blk < 1000) {
    int n = (blk - 992) * 256 + tid;
    int j = n & 63;
    bf16x8 o0 = {}, z = {};
    o0[0] = f2bf(S[j]); o0[1] = f2bf(S[64 + j]); o0[2] = f2bf(S[128 + j]);
    __hip_bfloat16* dst = PT + (size_t)n * K2 + 1760;
    *(bf16x8*)dst = o0;
    *(bf16x8*)(dst + 8) = z;
    *(bf16x8*)(dst + 16) = z;
    *(bf16x8*)(dst + 24) = z;
  } else {                                           // ---- w1m[c][b] = Mw1[c]·g[b] + mb1[c]
    int c0 = (blk - 1000) * 8;
    const float* src = Mw1 + (size_t)c0 * 720;
    for (int i = tid; i < 1440; i += 256)
      *(float4*)&smem[i * 4] = *(const float4*)(src + i * 4);
    __syncthreads();
    int rg = tid >> 5, b = tid & 31;
    const float* wr = &smem[rg * 720];
    float acc = 0.f;
    for (int k = 0; k < C720; k += 4) {
      float4 wv = *(const float4*)(wr + k);
      acc += wv.x * gT[(k    ) * 32 + b];
      acc += wv.y * gT[(k + 1) * 32 + b];
      acc += wv.z * gT[(k + 2) * 32 + b];
      acc += wv.w * gT[(k + 3) * 32 + b];
    }
    int c = c0 + rg;
    w1m[c * 32 + b] = acc + mb1[c];
  }
}

// ================= K6: wagg =================
__global__ __launch_bounds__(256) void k_wagg(const __hip_bfloat16* __restrict__ Wcatb,
    const int* __restrict__ rowptr, const int* __restrict__ colx, const float* __restrict__ dinv,
    __hip_bfloat16* __restrict__ Waggb) {
  int w = blockIdx.x * 4 + (threadIdx.x >> 6);
  int lane = threadIdx.x & 63;
  const int i3 = 1536 + lane * 8;
  const bool t3 = i3 < K2;
  __hip_bfloat16* drow = Waggb + (size_t)w * K2;
  if (w >= NV) {
    bf16x8 z = {};
    *(bf16x8*)(drow + lane * 8) = z;
    *(bf16x8*)(drow + 512 + lane * 8) = z;
    *(bf16x8*)(drow + 1024 + lane * 8) = z;
    if (t3) *(bf16x8*)(drow + i3) = z;
    return;
  }
  int r0 = rowptr[w], r1 = rowptr[w + 1];
  float a0[8] = {}, a1[8] = {}, a2[8] = {}, a3[8] = {};
  for (int i = r0; i < r1; ++i) {
    int u = colx[i];
    float wt = dinv[u];
    const __hip_bfloat16* row = Wcatb + (size_t)u * K2;
    bf16x8 x0 = *(const bf16x8*)(row + lane * 8);
    bf16x8 x1 = *(const bf16x8*)(row + 512 + lane * 8);
    bf16x8 x2 = *(const bf16x8*)(row + 1024 + lane * 8);
    #pragma unroll
    for (int e = 0; e < 8; ++e) {
      a0[e] += wt * bf2f(x0[e]);
      a1[e] += wt * bf2f(x1[e]);
      a2[e] += wt * bf2f(x2[e]);
    }
    if (t3) {
      bf16x8 x3 = *(const bf16x8*)(row + i3);
      #pragma unroll
      for (int e = 0; e < 8; ++e) a3[e] += wt * bf2f(x3[e]);
    }
  }
  float dv = dinv[w];
  bf16x8 o0, o1, o2, o3;
  #pragma unroll
  for (int e = 0; e < 8; ++e) {
    o0[e] = f2bf(a0[e] * dv); o1[e] = f2bf(a1[e] * dv);
    o2[e] = f2bf(a2[e] * dv); o3[e] = f2bf(a3[e] * dv);
  }
  *(bf16x8*)(drow + lane * 8) = o0;
  *(bf16x8*)(drow + 512 + lane * 8) = o1;
  *(bf16x8*)(drow + 1024 + lane * 8) = o2;
  if (t3) *(bf16x8*)(drow + i3) = o3;
}

// ================= K7: bf16 MFMA GEMM (m97 128², XCD-swizzled): p1 = dinv*leaky(Wagg @ PT^T + bg1) =================
__global__ __launch_bounds__(256) void k_mfma_gemm(
    const __hip_bfloat16* __restrict__ A, const __hip_bfloat16* __restrict__ BT,
    const float* __restrict__ bg1, const float* __restrict__ dinv,
    __hip_bfloat16* __restrict__ p1) {
  __shared__ __hip_bfloat16 As[128 * 64];
  __shared__ __hip_bfloat16 Bs[128 * 64];
  const int tid = threadIdx.x;
  const int wid = tid >> 6, lane = tid & 63;
  const int orig = blockIdx.y * gridDim.x + blockIdx.x;   // 864 blocks, 108/XCD
  const int swz = (orig & 7) * 108 + (orig >> 3);
  const int bxid = swz % (MPAD / 128), byid = swz / (MPAD / 128);
  const int m0 = bxid * 128, n0 = byid * 128;
  const int wr = wid >> 1, wc = wid & 1;
  const int l15 = lane & 15, lhi = lane >> 4;
  const int lk = lhi * 8;

  f32x4 acc[4][4];
  #pragma unroll
  for (int i = 0; i < 4; ++i)
    #pragma unroll
    for (int j = 0; j < 4; ++j) acc[i][j] = (f32x4){0.f, 0.f, 0.f, 0.f};

  const __hip_bfloat16* ag = A  + (size_t)(m0 + (tid >> 3)) * K2 + (tid & 7) * 8;
  const __hip_bfloat16* bg = BT + (size_t)(n0 + (tid >> 3)) * K2 + (tid & 7) * 8;
  const int lbase = wid * 512;

  for (int kt = 0; kt < K2; kt += 64) {
    #pragma unroll
    for (int p = 0; p < 4; ++p) {
      gload16(ag + kt + (size_t)(p * 32) * K2, (void*)&As[p * 2048 + lbase]);
      gload16(bg + kt + (size_t)(p * 32) * K2, (void*)&Bs[p * 2048 + lbase]);
    }
    __syncthreads();
    #pragma unroll
    for (int ks = 0; ks < 2; ++ks) {
      bf16x8 af[4], bf[4];
      #pragma unroll
      for (int mf = 0; mf < 4; ++mf)
        af[mf] = *(const bf16x8*)&As[(wr * 64 + mf * 16 + l15) * 64 + ks * 32 + lk];
      #pragma unroll
      for (int nf = 0; nf < 4; ++nf)
        bf[nf] = *(const bf16x8*)&Bs[(wc * 64 + nf * 16 + l15) * 64 + ks * 32 + lk];
      #pragma unroll
      for (int mf = 0; mf < 4; ++mf)
        #pragma unroll
        for (int nf = 0; nf < 4; ++nf)
          acc[mf][nf] = __builtin_amdgcn_mfma_f32_16x16x32_bf16(af[mf], bf[nf], acc[mf][nf], 0, 0, 0);
    }
    __syncthreads();
  }

  float bgv[4];
  #pragma unroll
  for (int nf = 0; nf < 4; ++nf) bgv[nf] = bg1[nf * 16 + l15];
  #pragma unroll
  for (int mf = 0; mf < 4; ++mf) {
    #pragma unroll
    for (int r = 0; r < 4; ++r) {
      int v = m0 + wr * 64 + mf * 16 + lhi * 4 + r;
      if (v >= NV) continue;
      float dv = dinv[v];
      __hip_bfloat16* pr = p1 + (size_t)v * NBIG + n0 + wc * 64;
      #pragma unroll
      for (int nf = 0; nf < 4; ++nf) {
        int jj = nf * 16 + l15;
        float x = acc[mf][nf][r] + bgv[nf];
        x = x > 0.f ? x : 0.01f * x;
        pr[jj] = (__hip_bfloat16)(x * dv);
      }
    }
  }
}

// ================= K9: BACK mega-kernel: t1 (block per vertex) | coordw =================
__global__ __launch_bounds__(256) void k_back(const __hip_bfloat16* __restrict__ p1,
    const int* __restrict__ rowptr, const int* __restrict__ colx, const float* __restrict__ dinv,
    const float* __restrict__ Wg2, const float* __restrict__ bg2,
    const float* __restrict__ Ww2, const float* __restrict__ bw2, const float* __restrict__ w1m,
    __hip_bfloat16* __restrict__ p2, float* __restrict__ out) {
  __shared__ float wg[2048];
  __shared__ float g[32 * 66];
  const int blk = blockIdx.x, tid = threadIdx.x;
  if (blk < NV) {                                    // ---- t1
    const int v = blk;
    for (int i = tid; i < 2048; i += 256) wg[i] = Wg2[i];
    const int r0 = rowptr[v], r1 = rowptr[v + 1];
    const int b = tid >> 3, j0 = (tid & 7) * 8;
    float a[8] = {};
    const short* base = (const short*)p1 + tid * 8;
    for (int i = r0; i < r1; ++i) {
      int u = colx[i];
      bf16x8 x = *(const bf16x8*)(base + (size_t)u * NBIG);
      #pragma unroll
      for (int e = 0; e < 8; ++e) a[e] += bf2f(x[e]);
    }
    #pragma unroll
    for (int e = 0; e < 8; e += 2)
      *(float2*)&g[b * 66 + j0 + e] = (float2){a[e], a[e + 1]};
    __syncthreads();
    const float dv = dinv[v];
    const int jg = tid & 7;
    float o0 = 0.f, o1 = 0.f, o2 = 0.f, o3 = 0.f;
    const float* gr = &g[b * 66];
    #pragma unroll 8
    for (int j = 0; j < 64; ++j) {
      float s = gr[j];
      const float* w = &wg[j * 32 + jg];
      o0 += s * w[0]; o1 += s * w[8]; o2 += s * w[16]; o3 += s * w[24];
    }
    __hip_bfloat16* pr = p2 + (size_t)v * 1024 + b * 32 + jg;
    float x0 = o0 * dv + bg2[jg];       x0 = x0 > 0.f ? x0 : 0.01f * x0;
    float x1 = o1 * dv + bg2[jg + 8];   x1 = x1 > 0.f ? x1 : 0.01f * x1;
    float x2 = o2 * dv + bg2[jg + 16];  x2 = x2 > 0.f ? x2 : 0.01f * x2;
    float x3 = o3 * dv + bg2[jg + 24];  x3 = x3 > 0.f ? x3 : 0.01f * x3;
    pr[0]  = (__hip_bfloat16)(x0 * dv);
    pr[8]  = (__hip_bfloat16)(x1 * dv);
    pr[16] = (__hip_bfloat16)(x2 * dv);
    pr[24] = (__hip_bfloat16)(x3 * dv);
  } else {                                           // ---- coordw
    int v = (blk - NV) * 8 + (tid >> 5);
    int b = tid & 31;
    if (v >= NV) return;
    const float* wr = Ww2 + (size_t)v * 224;
    float acc = 0.f;
    for (int c = 0; c < 224; c += 4) {
      float4 wv = *(const float4*)(wr + c);
      acc += wv.x * w1m[(c    ) * 32 + b];
      acc += wv.y * w1m[(c + 1) * 32 + b];
      acc += wv.z * w1m[(c + 2) * 32 + b];
      acc += wv.w * w1m[(c + 3) * 32 + b];
    }
    acc += bw2[v];
    out[((size_t)b * NV + v) * 4 + 3] = 1.f / (1.f + expf(-acc));
  }
}

// ================= K10: layer3 — block per vertex -> out[...,0:3) =================
__global__ __launch_bounds__(128) void k_t2(const __hip_bfloat16* __restrict__ p2,
    const int* __restrict__ rowptr, const int* __restrict__ colx, const float* __restrict__ dinv,
    const float* __restrict__ Wg3, const float* __restrict__ bg3, float* __restrict__ out) {
  __shared__ float wg[96];
  __shared__ float g[32 * 33];
  const int v = blockIdx.x, tid = threadIdx.x;
  if (tid < 96) wg[tid] = Wg3[tid];
  const int r0 = rowptr[v], r1 = rowptr[v + 1];
  const int b = tid >> 2, j0 = (tid & 3) * 8;
  float a[8] = {};
  const short* base = (const short*)p2 + tid * 8;
  for (int i = r0; i < r1; ++i) {
    int u = colx[i];
    bf16x8 x = *(const bf16x8*)(base + (size_t)u * 1024);
    #pragma unroll
    for (int e = 0; e < 8; ++e) a[e] += bf2f(x[e]);
  }
  #pragma unroll
  for (int e = 0; e < 8; ++e) g[b * 33 + j0 + e] = a[e];
  __syncthreads();
  if (tid < 96) {
    int bb = tid & 31, k = tid >> 5;
    float acc = 0.f;
    #pragma unroll 8
    for (int j2 = 0; j2 < 32; ++j2)
      acc += g[bb * 33 + j2] * wg[j2 * 3 + k];
    out[((size_t)bb * NV + v) * 4 + k] = acc * dinv[v] + bg3[k];
  }
}

extern "C" void kernel_launch(void* const* d_in, const int* in_sizes, int n_in,
                              void* d_out, int out_size, void* d_ws, size_t ws_size,
                              hipStream_t stream) {
  const float* img = (const float*)d_in[0];
  const int*   ei  = (const int*)d_in[1];
  const float* Wx  = (const float*)d_in[2];
  const float* bx  = (const float*)d_in[3];
  const float* Wy  = (const float*)d_in[4];
  const float* by  = (const float*)d_in[5];
  const float* Wz1 = (const float*)d_in[6];
  const float* bz1 = (const float*)d_in[7];
  const float* Wz2 = (const float*)d_in[8];
  const float* bz2 = (const float*)d_in[9];
  const float* Ww1 = (const float*)d_in[10];
  const float* bw1 = (const float*)d_in[11];
  const float* Ww2 = (const float*)d_in[12];
  const float* bw2 = (const float*)d_in[13];
  const float* Wg1 = (const float*)d_in[14];
  const float* bg1 = (const float*)d_in[15];
  const float* Wg2 = (const float*)d_in[16];
  const float* bg2 = (const float*)d_in[17];
  const float* Wg3 = (const float*)d_in[18];
  const float* bg3 = (const float*)d_in[19];
  float* out = (float*)d_out;
  int E = in_sizes[1] / 2;

  char* ws = (char*)d_ws;
  __hip_bfloat16* p1     = (__hip_bfloat16*)(ws + 0ULL);          // 28,311,552 [6912][2048]
  __hip_bfloat16* p2     = (__hip_bfloat16*)(ws + 28311552ULL);   // 14,155,776 [6912][1024]
  __hip_bfloat16* Wcatb  = (__hip_bfloat16*)(ws + 42467328ULL);   // 24,772,608 [6912][1792]
  __hip_bfloat16* Waggb  = (__hip_bfloat16*)(ws + 67239936ULL);   // 24,772,608
  float*          P      = (float*)(ws + 92012544ULL);            // 12,582,912 [1536][2048]
  __hip_bfloat16* PT     = (__hip_bfloat16*)(ws + 104595456ULL);  //  7,340,032 [2048][1792]
  float*          Z1T    = (float*)(ws + 111935488ULL);           //  1,605,632
  float*          Mw1    = (float*)(ws + 113541120ULL);           //    645,120 [224][720]
  float*          gT     = (float*)(ws + 114186240ULL);           //     92,160
  float*          w1m    = (float*)(ws + 114278400ULL);           //     28,672
  float*          S      = (float*)(ws + 114307072ULL);           //      1,024
  float*          mb1    = (float*)(ws + 114308096ULL);           //      1,024
  float*          dinv   = (float*)(ws + 114309120ULL);           //     27,648
  int*            rowptr = (int*)(ws + 114336768ULL);             //     27,648
  int*            colx   = (int*)(ws + 114364416ULL);             //    196,608
  int*            deg    = (int*)(ws + 114561024ULL);             //     27,648
  int*            cursor = (int*)(ws + 114588672ULL);             //     27,648

  k_front<<<12483, 256, 0, stream>>>(img, Wg1, Wx, Wy, Wz2, bx, by, bz2, Ww1, bw1,
                                     P, gT, Wcatb, S, Mw1, mb1, deg);
  k_deg<<<(E + 255) / 256, 256, 0, stream>>>(ei, E, deg);
  k_scan<<<1, 256, 0, stream>>>(deg, rowptr, dinv, cursor);
  k_fill<<<(E + NV + 255) / 256, 256, 0, stream>>>(ei, E, cursor, colx);
  k_head1<<<1568, 256, 0, stream>>>(Wz1, bz1, gT, Z1T);
  k_s3<<<1028, 256, 0, stream>>>(P, Z1T, Mw1, mb1, gT, Wg1, S, PT, w1m);
  k_wagg<<<MPAD / 4, 256, 0, stream>>>(Wcatb, rowptr, colx, dinv, Waggb);
  k_mfma_gemm<<<dim3(MPAD / 128, NBIG / 128), 256, 0, stream>>>(Waggb, PT, bg1, dinv, p1);
  k_back<<<NV + 862, 256, 0, stream>>>(p1, rowptr, colx, dinv, Wg2, bg2, Ww2, bw2, w1m, p2, out);
  k_t2<<<NV, 128, 0, stream>>>(p2, rowptr, colx, dinv, Wg3, bg3, out);
}

// Round 14
// 312.950 us; speedup vs baseline: 1.1305x; 1.0430x over previous
//
#include <hip/hip_runtime.h>
#include <hip/hip_bf16.h>
#include <math.h>

#define NV 6890
#define BATCH 32
#define C720 720
#define HW 56
#define K2 1792          // x[0,720) 0[720,768) y[768,1488) 0[1488,1536) z[1536,1760) bias[1760,1763) 0..1792
#define NBIG 2048
#define MPAD 6912

typedef __attribute__((ext_vector_type(8))) short bf16x8;
typedef __attribute__((ext_vector_type(4))) float f32x4;

__device__ inline void gload16(const void* g, void* l) {
  __builtin_amdgcn_global_load_lds((const __attribute__((address_space(1))) void*)g,
                                   (__attribute__((address_space(3))) void*)l, 16, 0, 0);
}
__device__ inline float bf2f(short s) {
  union { unsigned u; float f; } c; c.u = ((unsigned)(unsigned short)s) << 16; return c.f;
}
__device__ inline short f2bf(float f) {
  __hip_bfloat16 h = (__hip_bfloat16)f; return *(short*)&h;
}

// ================= K1: FRONT mega-kernel =================
// blk [0,5762): imgred (+P gap zero) | [5762,11810): wcat | [11810,12482): Mw1 (672 strided)
// blk 12482: S + mb1 + deg-zero.  All sections depend only on inputs; share HBM pipe.
__global__ __launch_bounds__(256) void k_front(const float* __restrict__ img,
    const float* __restrict__ Wg1,
    const float* __restrict__ Wx, const float* __restrict__ Wy, const float* __restrict__ Wz2,
    const float* __restrict__ bx, const float* __restrict__ by, const float* __restrict__ bz2,
    const float* __restrict__ Ww1, const float* __restrict__ bw1,
    float* __restrict__ P, float* __restrict__ gT, __hip_bfloat16* __restrict__ Wcatb,
    float* __restrict__ S, float* __restrict__ Mw1, float* __restrict__ mb1,
    int* __restrict__ deg) {
  __shared__ float rsumS[64];
  __shared__ float cpartW[4][56];
  __shared__ float csumS[56];
  const int blk = blockIdx.x, tid = threadIdx.x;
  if (blk < 5760) {                                  // ---- img tile reduction
    const int b = blk / C720, c = blk - b * C720;
    const float4* tp4 = (const float4*)(img + (size_t)blk * (HW * HW));
    const int wq = tid & 15, hg = tid >> 4;
    float4 cp = (float4){0.f, 0.f, 0.f, 0.f};
    #pragma unroll
    for (int r = 0; r < 4; ++r) {
      int h = hg + 16 * r;
      bool ok = (wq < 14) & (h < HW);
      float4 v = ok ? tp4[h * 14 + wq] : (float4){0.f, 0.f, 0.f, 0.f};
      cp.x += v.x; cp.y += v.y; cp.z += v.z; cp.w += v.w;
      float rsum = v.x + v.y + v.z + v.w;
      #pragma unroll
      for (int off = 1; off < 16; off <<= 1) rsum += __shfl_xor(rsum, off);
      if (wq == 0 && h < HW) rsumS[h] = rsum;
    }
    #pragma unroll
    for (int off = 16; off < 64; off <<= 1) {
      cp.x += __shfl_xor(cp.x, off); cp.y += __shfl_xor(cp.y, off);
      cp.z += __shfl_xor(cp.z, off); cp.w += __shfl_xor(cp.w, off);
    }
    int wave = tid >> 6, lane = tid & 63;
    if (lane < 14) *(float4*)&cpartW[wave][lane * 4] = cp;
    __syncthreads();
    if (tid < HW) csumS[tid] = cpartW[0][tid] + cpartW[1][tid] + cpartW[2][tid] + cpartW[3][tid];
    __syncthreads();
    if (tid < 64) {
      float ax = 0.f, ay = 0.f;
      #pragma unroll 4
      for (int l = 0; l < HW; ++l) {
        ax += csumS[l] * Wg1[l * 64 + tid];
        ay += rsumS[l] * Wg1[(HW + l) * 64 + tid];
      }
      P[(size_t)c * NBIG + b * 64 + tid] = ax * (1.f / HW);
      P[(size_t)(768 + c) * NBIG + b * 64 + tid] = ay * (1.f / HW);
    } else if (tid < 128) {
      int j = tid - 64;
      float s = (j < HW) ? csumS[j] : 0.f;
      #pragma unroll
      for (int off = 1; off < 64; off <<= 1) s += __shfl_xor(s, off);
      if (j == 0) gT[c * BATCH + b] = s * (1.f / (HW * HW));
    }
  } else if (blk < 5762) {                           // ---- zero P gap rows
    int r0 = (blk == 5760) ? 720 : 1488;
    float4* dst = (float4*)(P + (size_t)r0 * NBIG);
    for (int i = tid; i < 48 * NBIG / 4; i += 256) dst[i] = (float4){0.f, 0.f, 0.f, 0.f};
  } else if (blk < 11810) {                          // ---- wcat
    int idx = (blk - 5762) * 256 + tid;
    int v = idx / 224, c8 = (idx - v * 224) * 8;
    float val[8] = {};
    if (v < NV) {
      const float* s = nullptr;
      if (c8 < 720)                      s = Wx  + (size_t)v * 720 + c8;
      else if (c8 >= 768 && c8 < 1488)   s = Wy  + (size_t)v * 720 + (c8 - 768);
      else if (c8 >= 1536 && c8 < 1760)  s = Wz2 + (size_t)v * 224 + (c8 - 1536);
      if (s) {
        float4 a = *(const float4*)s, b4 = *(const float4*)(s + 4);
        val[0]=a.x; val[1]=a.y; val[2]=a.z; val[3]=a.w;
        val[4]=b4.x; val[5]=b4.y; val[6]=b4.z; val[7]=b4.w;
      } else if (c8 == 1760) {
        val[0] = bx[v]; val[1] = by[v]; val[2] = bz2[v];
      }
    }
    bf16x8 o;
    #pragma unroll
    for (int e = 0; e < 8; ++e) o[e] = f2bf(val[e]);
    *(bf16x8*)(Wcatb + (size_t)v * K2 + c8) = o;
  } else if (blk < 12482) {                          // ---- Mw1[224][720], strided
    int q = blk - 11810;
    int c = q / 3, chunk = q - c * 3;
    if (tid < 240) {
      int k = chunk * 240 + tid;
      float s = 0.f;
      for (int l = 0; l < HW; ++l) s += Ww1[(size_t)(c * HW + l) * 720 + k];
      Mw1[c * 720 + k] = s * (1.f / HW);
    }
  } else {                                           // ---- S + mb1 + deg zero
    if (tid < 64) {
      float s0 = 0, s1 = 0, s2 = 0;
      for (int l = 0; l < HW; ++l) {
        s0 += Wg1[l * 64 + tid];
        s1 += Wg1[(HW + l) * 64 + tid];
        s2 += Wg1[(112 + l) * 64 + tid];
      }
      S[tid] = s0; S[64 + tid] = s1; S[128 + tid] = s2;
    }
    if (tid < 224) {
      float s = 0.f;
      for (int l = 0; l < HW; ++l) s += bw1[tid * HW + l];
      mb1[tid] = s * (1.f / HW);
    }
    for (int v = tid; v < NV; v += 256) deg[v] = 0;
  }
}

// ================= K1b: edge-degree histogram =================
__global__ __launch_bounds__(256) void k_deg(const int* __restrict__ ei, int E, int* __restrict__ deg) {
  int e = blockIdx.x * 256 + threadIdx.x;
  if (e < E) atomicAdd(&deg[ei[E + e]], 1);
}

// ================= K1c: scan (1 block) =================
__global__ __launch_bounds__(256) void k_scan(const int* __restrict__ deg,
    int* __restrict__ rowptr, float* __restrict__ dinv, int* __restrict__ cursor) {
  __shared__ int sdata[256];
  const int tid = threadIdx.x;
  const int PER = 27;
  int base = tid * PER, loc[PER], tot = 0;
  #pragma unroll
  for (int i = 0; i < PER; ++i) {
    int idx = base + i;
    int c = (idx < NV) ? deg[idx] + 1 : 0;           // +1 self-loop
    loc[i] = tot; tot += c;
    if (idx < NV) dinv[idx] = rsqrtf((float)c);
  }
  sdata[tid] = tot; __syncthreads();
  for (int off = 1; off < 256; off <<= 1) {
    int v2 = sdata[tid];
    int a = (tid >= off) ? sdata[tid - off] : 0;
    __syncthreads();
    sdata[tid] = v2 + a;
    __syncthreads();
  }
  int excl = sdata[tid] - tot;
  #pragma unroll
  for (int i = 0; i < PER; ++i) {
    int idx = base + i;
    if (idx < NV) { int r = excl + loc[i]; rowptr[idx] = r; cursor[idx] = r; }
  }
  if (tid == 255) rowptr[NV] = sdata[255];
}

// ================= K1d: CSR fill =================
__global__ __launch_bounds__(256) void k_fill(const int* __restrict__ ei, int E,
    int* __restrict__ cursor, int* __restrict__ colx) {
  int i = blockIdx.x * 256 + threadIdx.x;
  int N = E + NV;
  if (i >= N) return;
  int s, d;
  if (i < E) { s = ei[i]; d = ei[E + i]; } else { s = d = i - E; }
  colx[atomicAdd(&cursor[d], 1)] = s;
}

// ================= K2: MID mega-kernel: head1 (Z1T) | wagg =================
// Both depend only on {front, fill} outputs.
__global__ __launch_bounds__(256) void k_mid(
    const float* __restrict__ Wz1, const float* __restrict__ bz1, const float* __restrict__ gT,
    const __hip_bfloat16* __restrict__ Wcatb, const int* __restrict__ rowptr,
    const int* __restrict__ colx, const float* __restrict__ dinv,
    float* __restrict__ Z1T, __hip_bfloat16* __restrict__ Waggb) {
  __shared__ float Ws[8 * 720];
  const int blk = blockIdx.x, tid = threadIdx.x;
  if (blk < 1568) {                                  // ---- head1: Z1T, LDS-staged weight rows
    const float* src = Wz1 + (size_t)blk * 8 * 720;
    for (int i = tid; i < 1440; i += 256)
      *(float4*)&Ws[i * 4] = *(const float4*)(src + i * 4);
    __syncthreads();
    int rg = tid >> 5, b = tid & 31;
    const float* wr = &Ws[rg * 720];
    float acc = 0.f;
    for (int k = 0; k < C720; k += 4) {
      float4 wv = *(const float4*)(wr + k);
      acc += wv.x * gT[(k    ) * 32 + b];
      acc += wv.y * gT[(k + 1) * 32 + b];
      acc += wv.z * gT[(k + 2) * 32 + b];
      acc += wv.w * gT[(k + 3) * 32 + b];
    }
    int r = blk * 8 + rg;
    Z1T[r * 32 + b] = acc + bz1[r];
  } else {                                           // ---- wagg
    int w = (blk - 1568) * 4 + (tid >> 6);
    int lane = tid & 63;
    const int i3 = 1536 + lane * 8;
    const bool t3 = i3 < K2;
    __hip_bfloat16* drow = Waggb + (size_t)w * K2;
    if (w >= NV) {
      if (w < MPAD) {
        bf16x8 z = {};
        *(bf16x8*)(drow + lane * 8) = z;
        *(bf16x8*)(drow + 512 + lane * 8) = z;
        *(bf16x8*)(drow + 1024 + lane * 8) = z;
        if (t3) *(bf16x8*)(drow + i3) = z;
      }
      return;
    }
    int r0 = rowptr[w], r1 = rowptr[w + 1];
    float a0[8] = {}, a1[8] = {}, a2[8] = {}, a3[8] = {};
    for (int i = r0; i < r1; ++i) {
      int u = colx[i];
      float wt = dinv[u];
      const __hip_bfloat16* row = Wcatb + (size_t)u * K2;
      bf16x8 x0 = *(const bf16x8*)(row + lane * 8);
      bf16x8 x1 = *(const bf16x8*)(row + 512 + lane * 8);
      bf16x8 x2 = *(const bf16x8*)(row + 1024 + lane * 8);
      #pragma unroll
      for (int e = 0; e < 8; ++e) {
        a0[e] += wt * bf2f(x0[e]);
        a1[e] += wt * bf2f(x1[e]);
        a2[e] += wt * bf2f(x2[e]);
      }
      if (t3) {
        bf16x8 x3 = *(const bf16x8*)(row + i3);
        #pragma unroll
        for (int e = 0; e < 8; ++e) a3[e] += wt * bf2f(x3[e]);
      }
    }
    float dv = dinv[w];
    bf16x8 o0, o1, o2, o3;
    #pragma unroll
    for (int e = 0; e < 8; ++e) {
      o0[e] = f2bf(a0[e] * dv); o1[e] = f2bf(a1[e] * dv);
      o2[e] = f2bf(a2[e] * dv); o3[e] = f2bf(a3[e] * dv);
    }
    *(bf16x8*)(drow + lane * 8) = o0;
    *(bf16x8*)(drow + 512 + lane * 8) = o1;
    *(bf16x8*)(drow + 1024 + lane * 8) = o2;
    if (t3) *(bf16x8*)(drow + i3) = o3;
  }
}

// ================= K5: transp | z-head | bias cols | w1m =================
__global__ __launch_bounds__(256) void k_s3(const float* __restrict__ P,
    const float* __restrict__ Z1T, const float* __restrict__ Mw1, const float* __restrict__ mb1,
    const float* __restrict__ gT,
    const float* __restrict__ Wg1, const float* __restrict__ S,
    __hip_bfloat16* __restrict__ PT, float* __restrict__ w1m) {
  __shared__ float smem[5760];
  const int blk = blockIdx.x, tid = threadIdx.x;
  if (blk < 768) {
    __hip_bfloat16* t = (__hip_bfloat16*)smem;
    int k0 = (blk % 24) * 64, n0 = (blk / 24) * 64;
    int tx = tid & 63, ty4 = tid >> 6;
    #pragma unroll
    for (int i = 0; i < 16; ++i) {
      int k = ty4 * 16 + i;
      t[k * 66 + tx] = (__hip_bfloat16)P[(size_t)(k0 + k) * NBIG + n0 + tx];
    }
    __syncthreads();
    #pragma unroll
    for (int i = 0; i < 16; ++i) {
      int n = ty4 * 16 + i;
      PT[(size_t)(n0 + n) * K2 + k0 + tx] = t[tx * 66 + n];
    }
  } else if (blk < 992) {
    float* Zl = smem;
    float* Wz = smem + 1848;
    const int c = blk - 768;
    for (int i = tid; i < 1792; i += 256) {
      int l = i >> 5, b = i & 31;
      Zl[l * 33 + b] = Z1T[(size_t)c * 1792 + i];
    }
    for (int i = tid; i < 3584; i += 256) Wz[i] = Wg1[112 * 64 + i];
    __syncthreads();
    int n0 = tid * 8, b = n0 >> 6, j0 = n0 & 63;
    float a[8] = {};
    for (int l = 0; l < HW; ++l) {
      float zv = Zl[l * 33 + b];
      const float* wr = &Wz[l * 64 + j0];
      #pragma unroll
      for (int e = 0; e < 8; ++e) a[e] += zv * wr[e];
    }
    #pragma unroll
    for (int e = 0; e < 8; ++e)
      PT[(size_t)(n0 + e) * K2 + 1536 + c] = (__hip_bfloat16)a[e];
  } else if (blk < 1000) {
    int n = (blk - 992) * 256 + tid;
    int j = n & 63;
    bf16x8 o0 = {}, z = {};
    o0[0] = f2bf(S[j]); o0[1] = f2bf(S[64 + j]); o0[2] = f2bf(S[128 + j]);
    __hip_bfloat16* dst = PT + (size_t)n * K2 + 1760;
    *(bf16x8*)dst = o0;
    *(bf16x8*)(dst + 8) = z;
    *(bf16x8*)(dst + 16) = z;
    *(bf16x8*)(dst + 24) = z;
  } else {                                           // ---- w1m[c][b] = Mw1[c]·g[b] + mb1[c]
    int c0 = (blk - 1000) * 8;
    const float* src = Mw1 + (size_t)c0 * 720;
    for (int i = tid; i < 1440; i += 256)
      *(float4*)&smem[i * 4] = *(const float4*)(src + i * 4);
    __syncthreads();
    int rg = tid >> 5, b = tid & 31;
    const float* wr = &smem[rg * 720];
    float acc = 0.f;
    for (int k = 0; k < C720; k += 4) {
      float4 wv = *(const float4*)(wr + k);
      acc += wv.x * gT[(k    ) * 32 + b];
      acc += wv.y * gT[(k + 1) * 32 + b];
      acc += wv.z * gT[(k + 2) * 32 + b];
      acc += wv.w * gT[(k + 3) * 32 + b];
    }
    int c = c0 + rg;
    w1m[c * 32 + b] = acc + mb1[c];
  }
}

// ================= K7: bf16 MFMA GEMM (m97 128², XCD-swizzled): p1 = dinv*leaky(Wagg @ PT^T + bg1) =================
__global__ __launch_bounds__(256) void k_mfma_gemm(
    const __hip_bfloat16* __restrict__ A, const __hip_bfloat16* __restrict__ BT,
    const float* __restrict__ bg1, const float* __restrict__ dinv,
    __hip_bfloat16* __restrict__ p1) {
  __shared__ __hip_bfloat16 As[128 * 64];
  __shared__ __hip_bfloat16 Bs[128 * 64];
  const int tid = threadIdx.x;
  const int wid = tid >> 6, lane = tid & 63;
  const int orig = blockIdx.y * gridDim.x + blockIdx.x;   // 864 blocks, 108/XCD
  const int swz = (orig & 7) * 108 + (orig >> 3);
  const int bxid = swz % (MPAD / 128), byid = swz / (MPAD / 128);
  const int m0 = bxid * 128, n0 = byid * 128;
  const int wr = wid >> 1, wc = wid & 1;
  const int l15 = lane & 15, lhi = lane >> 4;
  const int lk = lhi * 8;

  f32x4 acc[4][4];
  #pragma unroll
  for (int i = 0; i < 4; ++i)
    #pragma unroll
    for (int j = 0; j < 4; ++j) acc[i][j] = (f32x4){0.f, 0.f, 0.f, 0.f};

  const __hip_bfloat16* ag = A  + (size_t)(m0 + (tid >> 3)) * K2 + (tid & 7) * 8;
  const __hip_bfloat16* bg = BT + (size_t)(n0 + (tid >> 3)) * K2 + (tid & 7) * 8;
  const int lbase = wid * 512;

  for (int kt = 0; kt < K2; kt += 64) {
    #pragma unroll
    for (int p = 0; p < 4; ++p) {
      gload16(ag + kt + (size_t)(p * 32) * K2, (void*)&As[p * 2048 + lbase]);
      gload16(bg + kt + (size_t)(p * 32) * K2, (void*)&Bs[p * 2048 + lbase]);
    }
    __syncthreads();
    #pragma unroll
    for (int ks = 0; ks < 2; ++ks) {
      bf16x8 af[4], bf[4];
      #pragma unroll
      for (int mf = 0; mf < 4; ++mf)
        af[mf] = *(const bf16x8*)&As[(wr * 64 + mf * 16 + l15) * 64 + ks * 32 + lk];
      #pragma unroll
      for (int nf = 0; nf < 4; ++nf)
        bf[nf] = *(const bf16x8*)&Bs[(wc * 64 + nf * 16 + l15) * 64 + ks * 32 + lk];
      #pragma unroll
      for (int mf = 0; mf < 4; ++mf)
        #pragma unroll
        for (int nf = 0; nf < 4; ++nf)
          acc[mf][nf] = __builtin_amdgcn_mfma_f32_16x16x32_bf16(af[mf], bf[nf], acc[mf][nf], 0, 0, 0);
    }
    __syncthreads();
  }

  float bgv[4];
  #pragma unroll
  for (int nf = 0; nf < 4; ++nf) bgv[nf] = bg1[nf * 16 + l15];
  #pragma unroll
  for (int mf = 0; mf < 4; ++mf) {
    #pragma unroll
    for (int r = 0; r < 4; ++r) {
      int v = m0 + wr * 64 + mf * 16 + lhi * 4 + r;
      if (v >= NV) continue;
      float dv = dinv[v];
      __hip_bfloat16* pr = p1 + (size_t)v * NBIG + n0 + wc * 64;
      #pragma unroll
      for (int nf = 0; nf < 4; ++nf) {
        int jj = nf * 16 + l15;
        float x = acc[mf][nf][r] + bgv[nf];
        x = x > 0.f ? x : 0.01f * x;
        pr[jj] = (__hip_bfloat16)(x * dv);
      }
    }
  }
}

// ================= K9: BACK mega-kernel: t1 (block per vertex) | coordw =================
__global__ __launch_bounds__(256) void k_back(const __hip_bfloat16* __restrict__ p1,
    const int* __restrict__ rowptr, const int* __restrict__ colx, const float* __restrict__ dinv,
    const float* __restrict__ Wg2, const float* __restrict__ bg2,
    const float* __restrict__ Ww2, const float* __restrict__ bw2, const float* __restrict__ w1m,
    __hip_bfloat16* __restrict__ p2, float* __restrict__ out) {
  __shared__ float wg[2048];
  __shared__ float g[32 * 66];
  const int blk = blockIdx.x, tid = threadIdx.x;
  if (blk < NV) {                                    // ---- t1
    const int v = blk;
    for (int i = tid; i < 2048; i += 256) wg[i] = Wg2[i];
    const int r0 = rowptr[v], r1 = rowptr[v + 1];
    const int b = tid >> 3, j0 = (tid & 7) * 8;
    float a[8] = {};
    const short* base = (const short*)p1 + tid * 8;
    for (int i = r0; i < r1; ++i) {
      int u = colx[i];
      bf16x8 x = *(const bf16x8*)(base + (size_t)u * NBIG);
      #pragma unroll
      for (int e = 0; e < 8; ++e) a[e] += bf2f(x[e]);
    }
    #pragma unroll
    for (int e = 0; e < 8; e += 2)
      *(float2*)&g[b * 66 + j0 + e] = (float2){a[e], a[e + 1]};
    __syncthreads();
    const float dv = dinv[v];
    const int jg = tid & 7;
    float o0 = 0.f, o1 = 0.f, o2 = 0.f, o3 = 0.f;
    const float* gr = &g[b * 66];
    #pragma unroll 8
    for (int j = 0; j < 64; ++j) {
      float s = gr[j];
      const float* w = &wg[j * 32 + jg];
      o0 += s * w[0]; o1 += s * w[8]; o2 += s * w[16]; o3 += s * w[24];
    }
    __hip_bfloat16* pr = p2 + (size_t)v * 1024 + b * 32 + jg;
    float x0 = o0 * dv + bg2[jg];       x0 = x0 > 0.f ? x0 : 0.01f * x0;
    float x1 = o1 * dv + bg2[jg + 8];   x1 = x1 > 0.f ? x1 : 0.01f * x1;
    float x2 = o2 * dv + bg2[jg + 16];  x2 = x2 > 0.f ? x2 : 0.01f * x2;
    float x3 = o3 * dv + bg2[jg + 24];  x3 = x3 > 0.f ? x3 : 0.01f * x3;
    pr[0]  = (__hip_bfloat16)(x0 * dv);
    pr[8]  = (__hip_bfloat16)(x1 * dv);
    pr[16] = (__hip_bfloat16)(x2 * dv);
    pr[24] = (__hip_bfloat16)(x3 * dv);
  } else {                                           // ---- coordw
    int v = (blk - NV) * 8 + (tid >> 5);
    int b = tid & 31;
    if (v >= NV) return;
    const float* wr = Ww2 + (size_t)v * 224;
    float acc = 0.f;
    for (int c = 0; c < 224; c += 4) {
      float4 wv = *(const float4*)(wr + c);
      acc += wv.x * w1m[(c    ) * 32 + b];
      acc += wv.y * w1m[(c + 1) * 32 + b];
      acc += wv.z * w1m[(c + 2) * 32 + b];
      acc += wv.w * w1m[(c + 3) * 32 + b];
    }
    acc += bw2[v];
    out[((size_t)b * NV + v) * 4 + 3] = 1.f / (1.f + expf(-acc));
  }
}

// ================= K10: layer3 — block per vertex -> out[...,0:3) =================
__global__ __launch_bounds__(128) void k_t2(const __hip_bfloat16* __restrict__ p2,
    const int* __restrict__ rowptr, const int* __restrict__ colx, const float* __restrict__ dinv,
    const float* __restrict__ Wg3, const float* __restrict__ bg3, float* __restrict__ out) {
  __shared__ float wg[96];
  __shared__ float g[32 * 33];
  const int v = blockIdx.x, tid = threadIdx.x;
  if (tid < 96) wg[tid] = Wg3[tid];
  const int r0 = rowptr[v], r1 = rowptr[v + 1];
  const int b = tid >> 2, j0 = (tid & 3) * 8;
  float a[8] = {};
  const short* base = (const short*)p2 + tid * 8;
  for (int i = r0; i < r1; ++i) {
    int u = colx[i];
    bf16x8 x = *(const bf16x8*)(base + (size_t)u * 1024);
    #pragma unroll
    for (int e = 0; e < 8; ++e) a[e] += bf2f(x[e]);
  }
  #pragma unroll
  for (int e = 0; e < 8; ++e) g[b * 33 + j0 + e] = a[e];
  __syncthreads();
  if (tid < 96) {
    int bb = tid & 31, k = tid >> 5;
    float acc = 0.f;
    #pragma unroll 8
    for (int j2 = 0; j2 < 32; ++j2)
      acc += g[bb * 33 + j2] * wg[j2 * 3 + k];
    out[((size_t)bb * NV + v) * 4 + k] = acc * dinv[v] + bg3[k];
  }
}

extern "C" void kernel_launch(void* const* d_in, const int* in_sizes, int n_in,
                              void* d_out, int out_size, void* d_ws, size_t ws_size,
                              hipStream_t stream) {
  const float* img = (const float*)d_in[0];
  const int*   ei  = (const int*)d_in[1];
  const float* Wx  = (const float*)d_in[2];
  const float* bx  = (const float*)d_in[3];
  const float* Wy  = (const float*)d_in[4];
  const float* by  = (const float*)d_in[5];
  const float* Wz1 = (const float*)d_in[6];
  const float* bz1 = (const float*)d_in[7];
  const float* Wz2 = (const float*)d_in[8];
  const float* bz2 = (const float*)d_in[9];
  const float* Ww1 = (const float*)d_in[10];
  const float* bw1 = (const float*)d_in[11];
  const float* Ww2 = (const float*)d_in[12];
  const float* bw2 = (const float*)d_in[13];
  const float* Wg1 = (const float*)d_in[14];
  const float* bg1 = (const float*)d_in[15];
  const float* Wg2 = (const float*)d_in[16];
  const float* bg2 = (const float*)d_in[17];
  const float* Wg3 = (const float*)d_in[18];
  const float* bg3 = (const float*)d_in[19];
  float* out = (float*)d_out;
  int E = in_sizes[1] / 2;

  char* ws = (char*)d_ws;
  __hip_bfloat16* p1     = (__hip_bfloat16*)(ws + 0ULL);          // 28,311,552 [6912][2048]
  __hip_bfloat16* p2     = (__hip_bfloat16*)(ws + 28311552ULL);   // 14,155,776 [6912][1024]
  __hip_bfloat16* Wcatb  = (__hip_bfloat16*)(ws + 42467328ULL);   // 24,772,608 [6912][1792]
  __hip_bfloat16* Waggb  = (__hip_bfloat16*)(ws + 67239936ULL);   // 24,772,608
  float*          P      = (float*)(ws + 92012544ULL);            // 12,582,912 [1536][2048]
  __hip_bfloat16* PT     = (__hip_bfloat16*)(ws + 104595456ULL);  //  7,340,032 [2048][1792]
  float*          Z1T    = (float*)(ws + 111935488ULL);           //  1,605,632
  float*          Mw1    = (float*)(ws + 113541120ULL);           //    645,120 [224][720]
  float*          gT     = (float*)(ws + 114186240ULL);           //     92,160
  float*          w1m    = (float*)(ws + 114278400ULL);           //     28,672
  float*          S      = (float*)(ws + 114307072ULL);           //      1,024
  float*          mb1    = (float*)(ws + 114308096ULL);           //      1,024
  float*          dinv   = (float*)(ws + 114309120ULL);           //     27,648
  int*            rowptr = (int*)(ws + 114336768ULL);             //     27,648
  int*            colx   = (int*)(ws + 114364416ULL);             //    196,608
  int*            deg    = (int*)(ws + 114561024ULL);             //     27,648
  int*            cursor = (int*)(ws + 114588672ULL);             //     27,648

  k_front<<<12483, 256, 0, stream>>>(img, Wg1, Wx, Wy, Wz2, bx, by, bz2, Ww1, bw1,
                                     P, gT, Wcatb, S, Mw1, mb1, deg);
  k_deg<<<(E + 255) / 256, 256, 0, stream>>>(ei, E, deg);
  k_scan<<<1, 256, 0, stream>>>(deg, rowptr, dinv, cursor);
  k_fill<<<(E + NV + 255) / 256, 256, 0, stream>>>(ei, E, cursor, colx);
  k_mid<<<1568 + MPAD / 4, 256, 0, stream>>>(Wz1, bz1, gT, Wcatb, rowptr, colx, dinv,
                                             Z1T, Waggb);
  k_s3<<<1028, 256, 0, stream>>>(P, Z1T, Mw1, mb1, gT, Wg1, S, PT, w1m);
  k_mfma_gemm<<<dim3(MPAD / 128, NBIG / 128), 256, 0, stream>>>(Waggb, PT, bg1, dinv, p1);
  k_back<<<NV + 862, 256, 0, stream>>>(p1, rowptr, colx, dinv, Wg2, bg2, Ww2, bw2, w1m, p2, out);
  k_t2<<<NV, 128, 0, stream>>>(p2, rowptr, colx, dinv, Wg3, bg3, out);
}